// Round 6
// baseline (500.978 us; speedup 1.0000x reference)
//
#include <hip/hip_runtime.h>
#include <cfloat>
#include <cstdint>

// Problem constants (YOLOv8 640x640 head)
#define NB 64
#define NG 32
#define NC 80
#define NA 8400
#define KTOP 13
#define CHUNK 256
#define NCH 33                 // ceil(NA/CHUNK)
#define NCAND (NCH * KTOP)     // 429 candidates per (b,g)
#define GGRP 16                // g's per LDS group (2 groups of 16)

// ---------------------------------------------------------------------------
// Fused A+B: per block = (chunk of 256 anchors, batch b), 1 anchor/thread.
// 2 passes over g-groups of 16: compute align -> 16 KB LDS -> wave topk per g.
// Writes pb (float4), (mx, 1/denom) (float2), inside32, bestg, candidates.
// ---------------------------------------------------------------------------
__global__ __launch_bounds__(256) void fusedAB(
    const float* __restrict__ preds,          // (B, 84, A)
    const float* __restrict__ gt_bboxes,      // (B, G, 4)
    const int*   __restrict__ gt_classes,     // (B, G)
    const float* __restrict__ anchor_points,  // (A, 2)
    float4*      __restrict__ pb_ws,          // (B*A) decoded boxes
    float2*      __restrict__ aux_ws,         // (B*A) (mx, rdenom)
    unsigned*    __restrict__ inside32,       // (B*A)
    int*         __restrict__ bestg,          // (B*A)
    float*       __restrict__ candv,          // (B*G, NCH, 13)
    int*         __restrict__ candi,          // (B*G, NCH, 13)
    float*       __restrict__ out_sum)        // scalar, zeroed here
{
    __shared__ float sx1[NG], sy1[NG], sx2[NG], sy2[NG], sarea[NG];
    __shared__ int   scls[NG];
    __shared__ float salign[GGRP][CHUNK];     // 16 KB

    const int tid   = threadIdx.x;
    const int chunk = blockIdx.x;
    const int b     = blockIdx.y;
    const int abase = chunk * CHUNK;
    const int a0    = abase + tid;            // 1 anchor per thread
    const bool live = (a0 < NA);

    if (tid < NG) {
        const float* gb = gt_bboxes + ((size_t)b * NG + tid) * 4;
        const float x1 = gb[0], y1 = gb[1], x2 = gb[2], y2 = gb[3];
        sx1[tid] = x1; sy1[tid] = y1; sx2[tid] = x2; sy2[tid] = y2;
        sarea[tid] = (x2 - x1) * (y2 - y1);
        scls[tid]  = gt_classes[b * NG + tid];
    }
    if (b == 0 && chunk == 0 && tid == 0) out_sum[0] = 0.0f;
    __syncthreads();

    // ---- per-thread decode + softmax (once) ----
    float ax=0, ay=0, x1=0, y1=0, x2=0, y2=0, area=0, mx=0, rd=0;
    const float* cb = nullptr;
    if (live) {
        const float2 ap = *(const float2*)(anchor_points + (size_t)a0 * 2);
        ax = ap.x; ay = ap.y;

        const float* db = preds + (size_t)b * (4 + NC) * NA + a0;
        const float l  = db[0];
        const float t  = db[(size_t)NA];
        const float r  = db[(size_t)2 * NA];
        const float bo = db[(size_t)3 * NA];
        x1 = ax - l; y1 = ay - t; x2 = ax + r; y2 = ay + bo;
        area = (x2 - x1) * (y2 - y1);

        cb = db + (size_t)4 * NA;
        mx = -FLT_MAX;
#pragma unroll 8
        for (int c = 0; c < NC; ++c) mx = fmaxf(mx, cb[(size_t)c * NA]);
        float d = 0.0f;
#pragma unroll 8
        for (int c = 0; c < NC; ++c) d += __expf(cb[(size_t)c * NA] - mx);
        rd = 1.0f / d;
    }

    unsigned ins = 0u;
    int   bg = 0;
    float bi = -1.0f;       // strict > keeps first max (jnp.argmax)

    const int lane = tid & 63;
    const int wid  = tid >> 6;

    // ---- 2 groups of 16 g's: compute -> LDS -> per-wave topk ----
    for (int grp = 0; grp < 2; ++grp) {
        if (live) {
            for (int gg = 0; gg < GGRP; ++gg) {
                const int g = grp * GGRP + gg;
                const float bx1 = sx1[g], by1 = sy1[g], bx2 = sx2[g], by2 = sy2[g];
                const float sag = sarea[g];
                const float cvl = cb[(size_t)scls[g] * NA];
                const float ltx = fmaxf(x1, bx1), lty = fmaxf(y1, by1);
                const float rbx = fminf(x2, bx2), rby = fminf(y2, by2);
                const float w = fmaxf(rbx - ltx, 0.0f), h = fmaxf(rby - lty, 0.0f);
                const float inter = w * h;
                const float iou = inter / (area + sag - inter + 1e-7f);
                if (iou > bi) { bi = iou; bg = g; }
                const float cv = __expf(cvl - mx) * rd;
                const float al = sqrtf(fmaxf(iou, 1e-12f)) * sqrtf(fmaxf(cv, 1e-12f));
                const float dmin = fminf(fminf(ax - bx1, ay - by1), fminf(bx2 - ax, by2 - ay));
                if (dmin > 1e-9f) ins |= (1u << g);
                salign[gg][tid] = al;
            }
        }
        __syncthreads();

        // topk: wave wid handles gg = wid*4 .. wid*4+3 of this group
        for (int gi = 0; gi < 4; ++gi) {
            const int gg = wid * 4 + gi;
            const int g  = grp * GGRP + gg;
            float v[4]; int id[4];
#pragma unroll
            for (int j = 0; j < 4; ++j) { v[j] = -FLT_MAX; id[j] = 0x7FFFFFFF; }
            // lane sees exactly 4 slots (ascending index) -> list never overflows
#pragma unroll
            for (int k = 0; k < 4; ++k) {
                const int al = lane + 64 * k;
                const int a  = abase + al;
                const float x = (a < NA) ? salign[gg][al] : -FLT_MAX;
                if (x > v[3]) {
                    int j = 3;
                    while (j > 0 && v[j - 1] < x) { v[j] = v[j - 1]; id[j] = id[j - 1]; --j; }
                    v[j] = x; id[j] = a;
                }
            }
            float rv = -FLT_MAX; int ri = 0x7FFFFFFF;
            int p = 0;
            for (int r = 0; r < KTOP; ++r) {
                const float cvv = (p < 4) ? v[p]  : -FLT_MAX;
                const int   cii = (p < 4) ? id[p] : 0x7FFFFFFF;
                float bv = cvv; int bix = cii;
#pragma unroll
                for (int off = 32; off > 0; off >>= 1) {
                    const float ov = __shfl_xor(bv, off, 64);
                    const int   oi = __shfl_xor(bix, off, 64);
                    if (ov > bv || (ov == bv && oi < bix)) { bv = ov; bix = oi; }
                }
                if (cii == bix && p < 4) ++p;   // unique ids -> exactly one lane pops
                if (lane == r) { rv = bv; ri = bix; }
            }
            if (lane < KTOP) {
                const size_t base = ((size_t)(b * NG + g) * NCH + chunk) * KTOP + lane;
                candv[base] = rv; candi[base] = ri;
            }
        }
        __syncthreads();
    }

    if (live) {
        const int i = b * NA + a0;
        pb_ws[i]  = make_float4(x1, y1, x2, y2);
        aux_ws[i] = make_float2(mx, rd);
        inside32[i] = ins;
        bestg[i]    = bg;
    }
}

// ---------------------------------------------------------------------------
// Merge: one wave per (b,g): merge NCH*13=429 candidates -> final top-13
// anchor indices, written as a dense list (plain stores, NO global atomics).
// ---------------------------------------------------------------------------
__global__ __launch_bounds__(256) void mergeTopK(
    const float* __restrict__ candv,
    const int*   __restrict__ candi,
    int*         __restrict__ topk13)   // (B*G, 13)
{
    const int tid  = threadIdx.x;
    const int lane = tid & 63;
    const int row  = blockIdx.x * 4 + (tid >> 6);   // b*NG + g
    const size_t base = (size_t)row * NCAND;

    float v[7]; int id[7];
#pragma unroll
    for (int j = 0; j < 7; ++j) { v[j] = -FLT_MAX; id[j] = 0x7FFFFFFF; }
    // lane sees <=7 candidates; lex insertion (val desc, idx asc)
#pragma unroll
    for (int k = 0; k < 7; ++k) {
        const int j0 = lane + 64 * k;
        if (j0 < NCAND) {
            const float x  = candv[base + j0];
            const int   xi = candi[base + j0];
            if (x > v[6] || (x == v[6] && xi < id[6])) {
                int j = 6;
                while (j > 0 && (v[j - 1] < x || (v[j - 1] == x && id[j - 1] > xi))) {
                    v[j] = v[j - 1]; id[j] = id[j - 1]; --j;
                }
                v[j] = x; id[j] = xi;
            }
        }
    }
    int ri = 0x7FFFFFFF;
    int p = 0;
    for (int r = 0; r < KTOP; ++r) {
        const float cvv = (p < 7) ? v[p]  : -FLT_MAX;
        const int   cii = (p < 7) ? id[p] : 0x7FFFFFFF;
        float bv = cvv; int bi = cii;
#pragma unroll
        for (int off = 32; off > 0; off >>= 1) {
            const float ov = __shfl_xor(bv, off, 64);
            const int   oi = __shfl_xor(bi, off, 64);
            if (ov > bv || (ov == bv && oi < bi)) { bv = ov; bi = oi; }
        }
        if (cii == bi && p < 7) ++p;
        if (lane == r) ri = bi;
    }
    if (lane < KTOP) topk13[(size_t)row * KTOP + lane] = ri;
}

// ---------------------------------------------------------------------------
// Phase C: grid (33, B). Block scatters the batch's 416 winner ids into a
// 256-word LDS bitmask (LDS atomicOr: commutative, deterministic); each
// anchor thread reads one word. out: tb | tc | ts | fg | fg_sum
// ---------------------------------------------------------------------------
__global__ __launch_bounds__(256) void phaseC(
    const float*    __restrict__ gt_bboxes,
    const int*      __restrict__ gt_classes,
    const float*    __restrict__ preds,
    const float4*   __restrict__ pb_ws,
    const float2*   __restrict__ aux_ws,
    const int*      __restrict__ topk13,    // (B*G, 13)
    const unsigned* __restrict__ inside32,
    const int*      __restrict__ bestg,
    float*          __restrict__ out)
{
    __shared__ unsigned smask[CHUNK];
    __shared__ float ssum[4];

    const int tid   = threadIdx.x;
    const int b     = blockIdx.y;
    const int abase = blockIdx.x * CHUNK;
    const int a     = abase + tid;

    smask[tid] = 0u;
    __syncthreads();
    for (int j = tid; j < NG * KTOP; j += 256) {
        const int idx = topk13[(size_t)b * NG * KTOP + j];
        const int rel = idx - abase;
        if (rel >= 0 && rel < CHUNK)
            atomicOr(&smask[rel], 1u << (j / KTOP));
    }
    __syncthreads();

    bool fg = false;
    if (a < NA) {
        const int i = b * NA + a;
        unsigned m = smask[tid] & inside32[i];
        const int cnt = __popc(m);

        int tgt;
        if (cnt > 1)       { tgt = bestg[i];     fg = true;  }
        else if (cnt == 1) { tgt = __ffs(m) - 1; fg = true;  }
        else               { tgt = 0;            fg = false; }

        const float f = fg ? 1.0f : 0.0f;
        const float* gb = gt_bboxes + ((size_t)b * NG + tgt) * 4;
        const float gx1 = gb[0], gy1 = gb[1], gx2 = gb[2], gy2 = gb[3];
        *(float4*)(out + (size_t)i * 4) = make_float4(gx1 * f, gy1 * f, gx2 * f, gy2 * f);

        const size_t BA = (size_t)NB * NA;
        out[BA * 4 + i] = fg ? (float)gt_classes[b * NG + tgt] : 0.0f;

        float ts = 0.0f;
        if (fg) {
            // recompute align(a, tgt) with the same expressions/inputs as fusedAB
            const float4 pb = pb_ws[i];
            const float2 ax = aux_ws[i];
            const float areaA = (pb.z - pb.x) * (pb.w - pb.y);
            const float sag   = (gx2 - gx1) * (gy2 - gy1);
            const float ltx = fmaxf(pb.x, gx1), lty = fmaxf(pb.y, gy1);
            const float rbx = fminf(pb.z, gx2), rby = fminf(pb.w, gy2);
            const float w = fmaxf(rbx - ltx, 0.0f), h = fmaxf(rby - lty, 0.0f);
            const float inter = w * h;
            const float iou = inter / (areaA + sag - inter + 1e-7f);
            const int cls = gt_classes[b * NG + tgt];
            const float cv = __expf(preds[(size_t)b * (4 + NC) * NA + (size_t)(4 + cls) * NA + a] - ax.x) * ax.y;
            ts = sqrtf(fmaxf(iou, 1e-12f)) * sqrtf(fmaxf(cv, 1e-12f));
        }
        out[BA * 5 + i] = ts;
        out[BA * 6 + i] = f;
    }

    // fg.sum(): ballot per wave -> LDS -> one atomic per block (exact fp32 ints)
    const unsigned long long ball = __ballot(fg);
    if ((tid & 63) == 0) ssum[tid >> 6] = (float)__popcll(ball);
    __syncthreads();
    if (tid == 0) {
        const float s = ssum[0] + ssum[1] + ssum[2] + ssum[3];
        if (s != 0.0f) atomicAdd(&out[(size_t)NB * NA * 7], s);
    }
}

// ---------------------------------------------------------------------------
extern "C" void kernel_launch(void* const* d_in, const int* in_sizes, int n_in,
                              void* d_out, int out_size, void* d_ws, size_t ws_size,
                              hipStream_t stream) {
    const float* preds         = (const float*)d_in[0];
    const float* gt_bboxes     = (const float*)d_in[1];
    const int*   gt_classes    = (const int*)  d_in[2];
    const float* anchor_points = (const float*)d_in[3];
    // d_in[4] stride_tensor: unused by the reference math

    float* out = (float*)d_out;
    const size_t BA = (size_t)NB * NA;

    // workspace carve-up (16B-aligned first): pb | aux | inside | bestg | candv | candi | topk13
    char* ws = (char*)d_ws;
    size_t off = 0;
    float4*   pb_ws    = (float4*)(ws + off);   off += BA * sizeof(float4);
    float2*   aux_ws   = (float2*)(ws + off);   off += BA * sizeof(float2);
    unsigned* inside32 = (unsigned*)(ws + off); off += BA * sizeof(unsigned);
    int*      bestg    = (int*)(ws + off);      off += BA * sizeof(int);
    float*    candv    = (float*)(ws + off);    off += (size_t)NB * NG * NCAND * sizeof(float);
    int*      candi    = (int*)(ws + off);      off += (size_t)NB * NG * NCAND * sizeof(int);
    int*      topk13   = (int*)(ws + off);

    fusedAB<<<dim3(NCH, NB), 256, 0, stream>>>(preds, gt_bboxes, gt_classes, anchor_points,
                                               pb_ws, aux_ws, inside32, bestg,
                                               candv, candi, out + BA * 7);

    mergeTopK<<<NB * NG / 4, 256, 0, stream>>>(candv, candi, topk13);

    phaseC<<<dim3(NCH, NB), 256, 0, stream>>>(gt_bboxes, gt_classes, preds,
                                              pb_ws, aux_ws, topk13,
                                              inside32, bestg, out);
}

// Round 7
// 428.405 us; speedup vs baseline: 1.1694x; 1.1694x over previous
//
#include <hip/hip_runtime.h>
#include <cfloat>
#include <cstdint>

// Problem constants (YOLOv8 640x640 head)
#define NB 64
#define NG 32
#define NC 80
#define NA 8400
#define KTOP 13
#define CHUNK 256
#define NCH 33                 // ceil(NA/CHUNK)
#define NCAND (NCH * KTOP)     // 429 candidates per (b,g)
#define GGRP 16                // g's per LDS group (2 groups of 16)

// lex compare-exchange, descending (key desc, idx asc on ties) — branchless
#define CE(ka, ia, kb, ib)                                            \
    {                                                                 \
        const bool sw = (ka < kb) || (ka == kb && ia > ib);           \
        const unsigned tk = sw ? kb : ka;                             \
        const int      ti = sw ? ib : ia;                             \
        kb = sw ? ka : kb;  ib = sw ? ia : ib;                        \
        ka = tk;            ia = ti;                                  \
    }

// ---------------------------------------------------------------------------
// Fused A+B: per block = (chunk of 256 anchors, batch b), 1 anchor/thread.
// 2 passes over g-groups of 16: compute align -> 16 KB LDS -> wave topk per g.
// Topk: single-u32-key butterfly max (float bits of align>0 are monotone),
// consecutive-4 values per lane -> exact stable tie-break via ballot-first.
// ---------------------------------------------------------------------------
__global__ __launch_bounds__(256) void fusedAB(
    const float* __restrict__ preds,          // (B, 84, A)
    const float* __restrict__ gt_bboxes,      // (B, G, 4)
    const int*   __restrict__ gt_classes,     // (B, G)
    const float* __restrict__ anchor_points,  // (A, 2)
    float4*      __restrict__ pb_ws,          // (B*A) decoded boxes
    float2*      __restrict__ aux_ws,         // (B*A) (mx, rdenom)
    unsigned*    __restrict__ inside32,       // (B*A)
    int*         __restrict__ bestg,          // (B*A)
    float*       __restrict__ candv,          // (B*G, NCH, 13)
    int*         __restrict__ candi,          // (B*G, NCH, 13)
    float*       __restrict__ out_sum)        // scalar, zeroed here
{
    __shared__ float sx1[NG], sy1[NG], sx2[NG], sy2[NG], sarea[NG];
    __shared__ int   scls[NG];
    __shared__ float salign[GGRP][CHUNK];     // 16 KB

    const int tid   = threadIdx.x;
    const int chunk = blockIdx.x;
    const int b     = blockIdx.y;
    const int abase = chunk * CHUNK;
    const int a0    = abase + tid;            // 1 anchor per thread
    const bool live = (a0 < NA);

    if (tid < NG) {
        const float* gb = gt_bboxes + ((size_t)b * NG + tid) * 4;
        const float x1 = gb[0], y1 = gb[1], x2 = gb[2], y2 = gb[3];
        sx1[tid] = x1; sy1[tid] = y1; sx2[tid] = x2; sy2[tid] = y2;
        sarea[tid] = (x2 - x1) * (y2 - y1);
        scls[tid]  = gt_classes[b * NG + tid];
    }
    if (b == 0 && chunk == 0 && tid == 0) out_sum[0] = 0.0f;
    __syncthreads();

    // ---- per-thread decode + softmax (once) ----
    float ax=0, ay=0, x1=0, y1=0, x2=0, y2=0, area=0, mx=0, rd=0;
    const float* cb = nullptr;
    if (live) {
        const float2 ap = *(const float2*)(anchor_points + (size_t)a0 * 2);
        ax = ap.x; ay = ap.y;

        const float* db = preds + (size_t)b * (4 + NC) * NA + a0;
        const float l  = db[0];
        const float t  = db[(size_t)NA];
        const float r  = db[(size_t)2 * NA];
        const float bo = db[(size_t)3 * NA];
        x1 = ax - l; y1 = ay - t; x2 = ax + r; y2 = ay + bo;
        area = (x2 - x1) * (y2 - y1);

        cb = db + (size_t)4 * NA;
        mx = -FLT_MAX;
#pragma unroll 8
        for (int c = 0; c < NC; ++c) mx = fmaxf(mx, cb[(size_t)c * NA]);
        float d = 0.0f;
#pragma unroll 8
        for (int c = 0; c < NC; ++c) d += __expf(cb[(size_t)c * NA] - mx);
        rd = 1.0f / d;
    }

    unsigned ins = 0u;
    int   bg = 0;
    float bi = -1.0f;       // strict > keeps first max (jnp.argmax)

    const int lane = tid & 63;
    const int wid  = tid >> 6;

    // ---- 2 groups of 16 g's: compute -> LDS -> per-wave topk ----
    for (int grp = 0; grp < 2; ++grp) {
        if (live) {
            for (int gg = 0; gg < GGRP; ++gg) {
                const int g = grp * GGRP + gg;
                const float bx1 = sx1[g], by1 = sy1[g], bx2 = sx2[g], by2 = sy2[g];
                const float sag = sarea[g];
                const float cvl = cb[(size_t)scls[g] * NA];
                const float ltx = fmaxf(x1, bx1), lty = fmaxf(y1, by1);
                const float rbx = fminf(x2, bx2), rby = fminf(y2, by2);
                const float w = fmaxf(rbx - ltx, 0.0f), h = fmaxf(rby - lty, 0.0f);
                const float inter = w * h;
                const float iou = inter / (area + sag - inter + 1e-7f);
                if (iou > bi) { bi = iou; bg = g; }
                const float cv = __expf(cvl - mx) * rd;
                const float al = sqrtf(fmaxf(iou, 1e-12f)) * sqrtf(fmaxf(cv, 1e-12f));
                const float dmin = fminf(fminf(ax - bx1, ay - by1), fminf(bx2 - ax, by2 - ay));
                if (dmin > 1e-9f) ins |= (1u << g);
                salign[gg][tid] = al;     // al > 0 always
            }
        } else {
            // dead anchors (last chunk): sentinel key 0 (< any positive float)
            for (int gg = 0; gg < GGRP; ++gg) salign[gg][tid] = 0.0f;
        }
        __syncthreads();

        // topk: wave wid handles gg = wid*4 .. wid*4+3 of this group
        for (int gi = 0; gi < 4; ++gi) {
            const int gg = wid * 4 + gi;
            const int g  = grp * GGRP + gg;

            // lane takes 4 CONSECUTIVE values -> lane order == index order
            const float4 q = *(const float4*)&salign[gg][lane * 4];
            unsigned k0 = __float_as_uint(q.x), k1 = __float_as_uint(q.y);
            unsigned k2 = __float_as_uint(q.z), k3 = __float_as_uint(q.w);
            int i0 = abase + lane * 4, i1 = i0 + 1, i2 = i0 + 2, i3 = i0 + 3;

            // 5-CE lex sort desc (stable): (0,2)(1,3)(0,1)(2,3)(1,2)
            CE(k0, i0, k2, i2); CE(k1, i1, k3, i3);
            CE(k0, i0, k1, i1); CE(k2, i2, k3, i3);
            CE(k1, i1, k2, i2);

            unsigned rvk = 0u;
            int      ri  = 0x7FFFFFFF;
#pragma unroll
            for (int r = 0; r < KTOP; ++r) {
                // wave max of heads: single-u32 butterfly
                unsigned m = k0;
#pragma unroll
                for (int off = 32; off > 0; off >>= 1)
                    m = max(m, (unsigned)__shfl_xor((int)m, off, 64));
                // first lane holding the max = smallest anchor index (exact)
                const unsigned long long ball = __ballot(k0 == m);
                const int winner = __ffsll(ball) - 1;
                const int widx   = __shfl(i0, winner, 64);
                if (lane == winner) {        // pop head: fixed register shift
                    k0 = k1; i0 = i1; k1 = k2; i1 = i2; k2 = k3; i2 = i3; k3 = 0u;
                }
                if (lane == r) { rvk = m; ri = widx; }
            }
            if (lane < KTOP) {
                const size_t base = ((size_t)(b * NG + g) * NCH + chunk) * KTOP + lane;
                candv[base] = __uint_as_float(rvk);
                candi[base] = ri;
            }
        }
        __syncthreads();
    }

    if (live) {
        const int i = b * NA + a0;
        pb_ws[i]  = make_float4(x1, y1, x2, y2);
        aux_ws[i] = make_float2(mx, rd);
        inside32[i] = ins;
        bestg[i]    = bg;
    }
}

// ---------------------------------------------------------------------------
// Merge: one wave per (b,g): merge NCH*13=429 candidates -> final top-13
// anchor indices, written as a dense list (plain stores, NO global atomics).
// ---------------------------------------------------------------------------
__global__ __launch_bounds__(256) void mergeTopK(
    const float* __restrict__ candv,
    const int*   __restrict__ candi,
    int*         __restrict__ topk13)   // (B*G, 13)
{
    const int tid  = threadIdx.x;
    const int lane = tid & 63;
    const int row  = blockIdx.x * 4 + (tid >> 6);   // b*NG + g
    const size_t base = (size_t)row * NCAND;

    float v[7]; int id[7];
#pragma unroll
    for (int j = 0; j < 7; ++j) { v[j] = -FLT_MAX; id[j] = 0x7FFFFFFF; }
    // lane sees <=7 candidates; lex insertion (val desc, idx asc)
#pragma unroll
    for (int k = 0; k < 7; ++k) {
        const int j0 = lane + 64 * k;
        if (j0 < NCAND) {
            const float x  = candv[base + j0];
            const int   xi = candi[base + j0];
            if (x > v[6] || (x == v[6] && xi < id[6])) {
                int j = 6;
                while (j > 0 && (v[j - 1] < x || (v[j - 1] == x && id[j - 1] > xi))) {
                    v[j] = v[j - 1]; id[j] = id[j - 1]; --j;
                }
                v[j] = x; id[j] = xi;
            }
        }
    }
    int ri = 0x7FFFFFFF;
    int p = 0;
    for (int r = 0; r < KTOP; ++r) {
        const float cvv = (p < 7) ? v[p]  : -FLT_MAX;
        const int   cii = (p < 7) ? id[p] : 0x7FFFFFFF;
        float bv = cvv; int bi = cii;
#pragma unroll
        for (int off = 32; off > 0; off >>= 1) {
            const float ov = __shfl_xor(bv, off, 64);
            const int   oi = __shfl_xor(bi, off, 64);
            if (ov > bv || (ov == bv && oi < bi)) { bv = ov; bi = oi; }
        }
        if (cii == bi && p < 7) ++p;
        if (lane == r) ri = bi;
    }
    if (lane < KTOP) topk13[(size_t)row * KTOP + lane] = ri;
}

// ---------------------------------------------------------------------------
// Phase C: grid (33, B). Block scatters the batch's 416 winner ids into a
// 256-word LDS bitmask (LDS atomicOr: commutative, deterministic); each
// anchor thread reads one word. out: tb | tc | ts | fg | fg_sum
// ---------------------------------------------------------------------------
__global__ __launch_bounds__(256) void phaseC(
    const float*    __restrict__ gt_bboxes,
    const int*      __restrict__ gt_classes,
    const float*    __restrict__ preds,
    const float4*   __restrict__ pb_ws,
    const float2*   __restrict__ aux_ws,
    const int*      __restrict__ topk13,    // (B*G, 13)
    const unsigned* __restrict__ inside32,
    const int*      __restrict__ bestg,
    float*          __restrict__ out)
{
    __shared__ unsigned smask[CHUNK];
    __shared__ float ssum[4];

    const int tid   = threadIdx.x;
    const int b     = blockIdx.y;
    const int abase = blockIdx.x * CHUNK;
    const int a     = abase + tid;

    smask[tid] = 0u;
    __syncthreads();
    for (int j = tid; j < NG * KTOP; j += 256) {
        const int idx = topk13[(size_t)b * NG * KTOP + j];
        const int rel = idx - abase;
        if (rel >= 0 && rel < CHUNK)
            atomicOr(&smask[rel], 1u << (j / KTOP));
    }
    __syncthreads();

    bool fg = false;
    if (a < NA) {
        const int i = b * NA + a;
        unsigned m = smask[tid] & inside32[i];
        const int cnt = __popc(m);

        int tgt;
        if (cnt > 1)       { tgt = bestg[i];     fg = true;  }
        else if (cnt == 1) { tgt = __ffs(m) - 1; fg = true;  }
        else               { tgt = 0;            fg = false; }

        const float f = fg ? 1.0f : 0.0f;
        const float* gb = gt_bboxes + ((size_t)b * NG + tgt) * 4;
        const float gx1 = gb[0], gy1 = gb[1], gx2 = gb[2], gy2 = gb[3];
        *(float4*)(out + (size_t)i * 4) = make_float4(gx1 * f, gy1 * f, gx2 * f, gy2 * f);

        const size_t BA = (size_t)NB * NA;
        out[BA * 4 + i] = fg ? (float)gt_classes[b * NG + tgt] : 0.0f;

        float ts = 0.0f;
        if (fg) {
            // recompute align(a, tgt) with the same expressions/inputs as fusedAB
            const float4 pb = pb_ws[i];
            const float2 ax = aux_ws[i];
            const float areaA = (pb.z - pb.x) * (pb.w - pb.y);
            const float sag   = (gx2 - gx1) * (gy2 - gy1);
            const float ltx = fmaxf(pb.x, gx1), lty = fmaxf(pb.y, gy1);
            const float rbx = fminf(pb.z, gx2), rby = fminf(pb.w, gy2);
            const float w = fmaxf(rbx - ltx, 0.0f), h = fmaxf(rby - lty, 0.0f);
            const float inter = w * h;
            const float iou = inter / (areaA + sag - inter + 1e-7f);
            const int cls = gt_classes[b * NG + tgt];
            const float cv = __expf(preds[(size_t)b * (4 + NC) * NA + (size_t)(4 + cls) * NA + a] - ax.x) * ax.y;
            ts = sqrtf(fmaxf(iou, 1e-12f)) * sqrtf(fmaxf(cv, 1e-12f));
        }
        out[BA * 5 + i] = ts;
        out[BA * 6 + i] = f;
    }

    // fg.sum(): ballot per wave -> LDS -> one atomic per block (exact fp32 ints)
    const unsigned long long ball = __ballot(fg);
    if ((tid & 63) == 0) ssum[tid >> 6] = (float)__popcll(ball);
    __syncthreads();
    if (tid == 0) {
        const float s = ssum[0] + ssum[1] + ssum[2] + ssum[3];
        if (s != 0.0f) atomicAdd(&out[(size_t)NB * NA * 7], s);
    }
}

// ---------------------------------------------------------------------------
extern "C" void kernel_launch(void* const* d_in, const int* in_sizes, int n_in,
                              void* d_out, int out_size, void* d_ws, size_t ws_size,
                              hipStream_t stream) {
    const float* preds         = (const float*)d_in[0];
    const float* gt_bboxes     = (const float*)d_in[1];
    const int*   gt_classes    = (const int*)  d_in[2];
    const float* anchor_points = (const float*)d_in[3];
    // d_in[4] stride_tensor: unused by the reference math

    float* out = (float*)d_out;
    const size_t BA = (size_t)NB * NA;

    // workspace carve-up (16B-aligned first): pb | aux | inside | bestg | candv | candi | topk13
    char* ws = (char*)d_ws;
    size_t off = 0;
    float4*   pb_ws    = (float4*)(ws + off);   off += BA * sizeof(float4);
    float2*   aux_ws   = (float2*)(ws + off);   off += BA * sizeof(float2);
    unsigned* inside32 = (unsigned*)(ws + off); off += BA * sizeof(unsigned);
    int*      bestg    = (int*)(ws + off);      off += BA * sizeof(int);
    float*    candv    = (float*)(ws + off);    off += (size_t)NB * NG * NCAND * sizeof(float);
    int*      candi    = (int*)(ws + off);      off += (size_t)NB * NG * NCAND * sizeof(int);
    int*      topk13   = (int*)(ws + off);

    fusedAB<<<dim3(NCH, NB), 256, 0, stream>>>(preds, gt_bboxes, gt_classes, anchor_points,
                                               pb_ws, aux_ws, inside32, bestg,
                                               candv, candi, out + BA * 7);

    mergeTopK<<<NB * NG / 4, 256, 0, stream>>>(candv, candi, topk13);

    phaseC<<<dim3(NCH, NB), 256, 0, stream>>>(gt_bboxes, gt_classes, preds,
                                              pb_ws, aux_ws, topk13,
                                              inside32, bestg, out);
}